// Round 1
// baseline (888.714 us; speedup 1.0000x reference)
//
#include <hip/hip_runtime.h>

// LSTM: B=512, T=512, I=128, H=50, O=10, fp32.
// R5: (1) lstm_rec: barrier-free single-wave loop. __syncthreads forced
//     s_waitcnt vmcnt(0) each step, serializing the prefetch (R4's 1294cy/step
//     vs ~380 issue). Same-wave LDS is in-order; explicit lgkmcnt(0) after the
//     h write is sufficient. (2) W_hh pinned in VGPRs via empty asm (R4's
//     VGPR=84 proves compiler rematerialized 28 weight loads per step).
//     (3) xp stored [b][t][unit][gate] (gate-permuted W_ih/bias at prep) ->
//     one dwordx2 xp load/step; bias pre-added in xproj.
// (4) xproj: t-major tiles (contiguous 32KB x reads, 128B granule) + D restage
//     through LDS for coalesced 16B stores; was ~210us with 256KB-strided 16B
//     reads and scalar 2B stores.

#define BB 512
#define TT 512
#define II 128
#define HH 50
#define GG 200   // 4*H

typedef _Float16 half2v __attribute__((ext_vector_type(2)));
typedef _Float16 half4v __attribute__((ext_vector_type(4)));
typedef _Float16 half8v __attribute__((ext_vector_type(8)));
typedef float float4v __attribute__((ext_vector_type(4)));

#if defined(__has_builtin)
#if __has_builtin(__builtin_amdgcn_fdot2)
#define HAVE_FDOT2 1
#endif
#endif

__device__ __forceinline__ float fdot2f(half2v a, half2v b, float c) {
#ifdef HAVE_FDOT2
    return __builtin_amdgcn_fdot2(a, b, c, false);
#else
    return c + (float)a[0] * (float)b[0] + (float)a[1] * (float)b[1];
#endif
}

__device__ __forceinline__ float fsig(float x) {
    return 1.f / (1.f + __expf(-x));
}
__device__ __forceinline__ float ftanh(float x) {
    return 2.f * fsig(2.f * x) - 1.f;
}

// ---------------- Kernel 0: prep (once per launch) ----------------
// Gate permutation: gp = unit*4 + gate  <->  orig g = gate*50 + unit.
// wfrags: W_ih rows in PERMUTED order as f16 MFMA B-fragments
//         [nt 13][kc 4][lane 64][j 8]
// whh16:  W_hh rows padded to 56 f16, ORIGINAL order  [g 200][56]
// biasv:  b_ih + b_hh in PERMUTED order               [gp 200]
__global__ __launch_bounds__(256) void prep_kernel(
    const float* __restrict__ W_ih, const float* __restrict__ W_hh,
    const float* __restrict__ b_ih, const float* __restrict__ b_hh,
    _Float16* __restrict__ wfrags, _Float16* __restrict__ whh16,
    float* __restrict__ biasv)
{
    int idx = blockIdx.x * 256 + threadIdx.x;
    if (idx < 3328) {                       // 13*4*64 fragment slots
        int lane = idx & 63, kc = (idx >> 6) & 3, nt = idx >> 8;
        int gp = nt * 16 + (lane & 15);     // permuted gate index
        int k0 = kc * 32 + ((lane >> 4) & 3) * 8;
        half8v v;
        if (gp < GG) {
            int u = gp >> 2, j = gp & 3;
            const float* wr = W_ih + (size_t)(j * HH + u) * II + k0;
            #pragma unroll
            for (int q = 0; q < 8; ++q) v[q] = (_Float16)wr[q];
        } else {
            #pragma unroll
            for (int q = 0; q < 8; ++q) v[q] = (_Float16)0.f;
        }
        *(half8v*)(wfrags + (size_t)idx * 8) = v;
    } else if (idx < 3328 + 2800) {         // 200 rows * 14 quads
        int r = idx - 3328;
        int g = r / 14, j4 = r % 14;
        #pragma unroll
        for (int j = 0; j < 4; ++j) {
            int hidx = j4 * 4 + j;
            whh16[g * 56 + hidx] = (hidx < HH) ? (_Float16)W_hh[g * HH + hidx]
                                               : (_Float16)0.f;
        }
    } else if (idx < 3328 + 2800 + GG) {
        int gp = idx - 6128;
        int u = gp >> 2, j = gp & 3;
        biasv[gp] = b_ih[j * HH + u] + b_hh[j * HH + u];
    }
}

// ---------------- Kernel 1: xproj via MFMA, t-major tiles ----------------
// Block = (b, t-tile of 64). A = x[b][t0:t0+64][0:128] (contiguous 32KB).
// Output xp16[b][t - chunk][gp] f16, bias pre-added, coalesced 16B stores.
__global__ __launch_bounds__(256) void xproj_mfma(
    const float* __restrict__ x, const _Float16* __restrict__ wfrags,
    const float* __restrict__ biasv, _Float16* __restrict__ xp16,
    int t0, int tsh)
{
    __shared__ __align__(16) _Float16 afrag[4 * 4 * 64 * 8];  // 16 KB
    __shared__ __align__(16) _Float16 dtile[64 * GG];         // 25.6 KB
    const int tid = threadIdx.x;
    const int b = blockIdx.x >> tsh;
    const int tt = blockIdx.x & ((1 << tsh) - 1);
    const int trow0 = t0 + tt * 64;         // global t of tile row 0

    // Stage A: thread owns one fragment slot (16B): 2 float4 loads, 1 b128 write.
    // Wave reads 16 rows x 128B contiguous each -> full-cacheline coalescing.
    const float* xb = x + ((size_t)b * TT + trow0) * II;
    #pragma unroll
    for (int it = 0; it < 4; ++it) {
        int s = it * 256 + tid;             // slot in [0,1024)
        int l = s & 63, kc = (s >> 6) & 3, wq = s >> 8;
        int row = wq * 16 + (l & 15);
        int k0 = kc * 32 + ((l >> 4) & 3) * 8;
        const float4 v0 = *(const float4*)(xb + (size_t)row * II + k0);
        const float4 v1 = *(const float4*)(xb + (size_t)row * II + k0 + 4);
        half8v p;
        p[0] = (_Float16)v0.x; p[1] = (_Float16)v0.y;
        p[2] = (_Float16)v0.z; p[3] = (_Float16)v0.w;
        p[4] = (_Float16)v1.x; p[5] = (_Float16)v1.y;
        p[6] = (_Float16)v1.z; p[7] = (_Float16)v1.w;
        *(half8v*)(afrag + (size_t)s * 8) = p;
    }
    __syncthreads();

    const int w = tid >> 6;
    const int l = tid & 63;
    float4v acc[13];
    #pragma unroll
    for (int nt = 0; nt < 13; ++nt) acc[nt] = (float4v){0.f, 0.f, 0.f, 0.f};

    #pragma unroll
    for (int kc = 0; kc < 4; ++kc) {
        half8v a = *(half8v*)(afrag + (size_t)(((w * 4 + kc) * 64) + l) * 8);
        #pragma unroll
        for (int nt = 0; nt < 13; ++nt) {
            half8v bf = *(const half8v*)(wfrags + (size_t)(((nt * 4 + kc) * 64) + l) * 8);
            acc[nt] = __builtin_amdgcn_mfma_f32_16x16x32_f16(a, bf, acc[nt], 0, 0, 0);
        }
    }

    // D restage: col=lane&15 (permuted gate), row=(lane>>4)*4+reg (t-row).
    const int colb = l & 15, rq = l >> 4;
    #pragma unroll
    for (int nt = 0; nt < 13; ++nt) {
        int g = nt * 16 + colb;
        if (g < GG) {
            float bs = biasv[g];
            #pragma unroll
            for (int reg = 0; reg < 4; ++reg)
                dtile[(w * 16 + rq * 4 + reg) * GG + g] = (_Float16)(acc[nt][reg] + bs);
        }
    }
    __syncthreads();

    // Coalesced writeout: 64*200 f16 = 1600 x 16B contiguous.
    _Float16* outp = xp16 + ((size_t)b * (64 << tsh) + (size_t)tt * 64) * GG;
    #pragma unroll
    for (int it = 0; it < 7; ++it) {
        int idx = it * 256 + tid;
        if (idx < 1600) {
            float4v v = *(const float4v*)(dtile + (size_t)idx * 8);
            *(float4v*)(outp + (size_t)idx * 8) = v;
        }
    }
}

// ---------------- Kernel 2: recurrence (barrier-free single wave) --------
__global__ __launch_bounds__(64, 1) void lstm_rec(
    const _Float16* __restrict__ xp16, const _Float16* __restrict__ whh16,
    float* __restrict__ hs, float* __restrict__ cs, int Tc, int first)
{
    __shared__ __align__(16) _Float16 hbuf[64];
    const int b = blockIdx.x;
    const int k = threadIdx.x;
    const int kk = (k < HH) ? k : 0;

    // W_hh rows for unit kk, 4 gates; pinned in VGPRs (asm makes remat unsound).
    float4v wr0[7], wr1[7], wr2[7], wr3[7];
    #pragma unroll
    for (int j = 0; j < 7; ++j) {
        wr0[j] = *(const float4v*)(whh16 + (size_t)(kk      ) * 56 + j * 8);
        wr1[j] = *(const float4v*)(whh16 + (size_t)(kk +  50) * 56 + j * 8);
        wr2[j] = *(const float4v*)(whh16 + (size_t)(kk + 100) * 56 + j * 8);
        wr3[j] = *(const float4v*)(whh16 + (size_t)(kk + 150) * 56 + j * 8);
    }
    #pragma unroll
    for (int j = 0; j < 7; ++j)
        asm volatile("" : "+v"(wr0[j]), "+v"(wr1[j]), "+v"(wr2[j]), "+v"(wr3[j]));

    float c = 0.f;
    _Float16 hinit = (_Float16)0.f;
    if (!first && k < HH) {
        c = cs[b * HH + k];
        hinit = (_Float16)hs[b * HH + k];
    }
    hbuf[k] = hinit;
    asm volatile("s_waitcnt lgkmcnt(0)" ::: "memory");

    // xp: [b][t][unit*4+gate] -> one 8B load per step, contiguous 400B/step.
    const _Float16* xpb = xp16 + (size_t)b * Tc * GG + kk * 4;
    half4v pv[4];
    #pragma unroll
    for (int d = 0; d < 4; ++d) {
        int td = (d < Tc) ? d : (Tc - 1);
        pv[d] = *(const half4v*)(xpb + (size_t)td * GG);
    }

    float hlast = 0.f;
    #pragma unroll 4
    for (int t = 0; t < Tc; ++t) {
        const int s = t & 3;
        half4v p = pv[s];
        float aI = (float)p[0];
        float aF = (float)p[1];
        float aG = (float)p[2];
        float aO = (float)p[3];

        // refill slot s for t+4; stays in flight (no vmcnt drain anywhere)
        {
            int tn = t + 4; if (tn >= Tc) tn = Tc - 1;
            pv[s] = *(const half4v*)(xpb + (size_t)tn * GG);
        }

        half8v hv[7];
        #pragma unroll
        for (int j = 0; j < 7; ++j) hv[j] = *(half8v*)(hbuf + j * 8);

        #pragma unroll
        for (int j = 0; j < 7; ++j) {
            half2v* hp = (half2v*)&hv[j];
            #pragma unroll
            for (int q = 0; q < 4; ++q) {
                half2v hq = hp[q];
                aI = fdot2f(hq, ((half2v*)&wr0[j])[q], aI);
                aF = fdot2f(hq, ((half2v*)&wr1[j])[q], aF);
                aG = fdot2f(hq, ((half2v*)&wr2[j])[q], aG);
                aO = fdot2f(hq, ((half2v*)&wr3[j])[q], aO);
            }
        }
        float ii = fsig(aI), ff = fsig(aF), gg2 = ftanh(aG), oo = fsig(aO);
        c = ff * c + ii * gg2;
        float hn = oo * ftanh(c);
        // Single wave: ds ops are same-wave in-order; reads above consumed
        // (data dep through hn) before this write; lgkmcnt(0) gives RAW
        // visibility for next iteration. No s_barrier -> no vmcnt(0) drain.
        if (k < HH) hbuf[k] = (_Float16)hn;
        asm volatile("s_waitcnt lgkmcnt(0)" ::: "memory");
        hlast = hn;
    }
    if (k < HH) {
        hs[b * HH + k] = hlast;
        cs[b * HH + k] = c;
    }
}

// ---------------- Kernel 3: FC epilogue ----------------
__global__ __launch_bounds__(256) void fc_kernel(
    const float* __restrict__ hs, const float* __restrict__ W_fc,
    const float* __restrict__ b_fc, float* __restrict__ out)
{
    int idx = blockIdx.x * blockDim.x + threadIdx.x;   // 512*10
    if (idx < BB * 10) {
        int b = idx / 10, o = idx % 10;
        float a = b_fc[o];
        #pragma unroll
        for (int kx = 0; kx < HH; ++kx)
            a += hs[b * HH + kx] * W_fc[o * HH + kx];
        out[idx] = a;
    }
}

extern "C" void kernel_launch(void* const* d_in, const int* in_sizes, int n_in,
                              void* d_out, int out_size, void* d_ws, size_t ws_size,
                              hipStream_t stream)
{
    const float* x    = (const float*)d_in[0];
    const float* W_ih = (const float*)d_in[1];
    const float* W_hh = (const float*)d_in[2];
    const float* b_ih = (const float*)d_in[3];
    const float* b_hh = (const float*)d_in[4];
    const float* W_fc = (const float*)d_in[5];
    const float* b_fc = (const float*)d_in[6];
    float* out = (float*)d_out;
    char* wsb = (char*)d_ws;

    const size_t hs_b = (size_t)BB * HH * sizeof(float);        // 102400
    const size_t wfrags_b = (size_t)13 * 4 * 64 * 8 * 2;        // 53248
    const size_t whh_b = (size_t)GG * 56 * 2;                   // 22400
    const size_t bias_b = 1024;
    const size_t fixed_b = 2 * hs_b + wfrags_b + whh_b + bias_b;

    int Tc = TT;
    while (Tc > 64 && (size_t)BB * Tc * GG * 2 + fixed_b > ws_size)
        Tc >>= 1;
    int tsh = 0; { int v = Tc >> 6; while (v > 1) { v >>= 1; ++tsh; } }

    _Float16* xp16 = (_Float16*)wsb;
    char* p = wsb + (size_t)BB * Tc * GG * 2;
    float* hsbuf = (float*)p;            p += hs_b;
    float* csbuf = (float*)p;            p += hs_b;
    _Float16* wfrags = (_Float16*)p;     p += wfrags_b;
    _Float16* whh16 = (_Float16*)p;      p += whh_b;
    float* biasv = (float*)p;

    prep_kernel<<<25, 256, 0, stream>>>(W_ih, W_hh, b_ih, b_hh, wfrags, whh16, biasv);

    const int nch = TT / Tc;
    for (int j = 0; j < nch; ++j) {
        xproj_mfma<<<BB * (Tc >> 6), 256, 0, stream>>>(x, wfrags, biasv, xp16, j * Tc, tsh);
        lstm_rec<<<BB, 64, 0, stream>>>(xp16, whh16, hsbuf, csbuf, Tc, j == 0);
    }
    fc_kernel<<<(BB * 10 + 255) / 256, 256, 0, stream>>>(hsbuf, W_fc, b_fc, out);
}